// Round 24
// baseline (495.179 us; speedup 1.0000x reference)
//
// NRField rev24: r23 with the WORKSPACE OVERLAP fixed (r23's absmax 659 was
// W32 pack [bytes 434k..827k] colliding with TB2_BYTE_OFF=524288 - both the
// 32-order weights and table lvl0 were clobbered; the 32x32 math was never
// actually tested). TB2 moved to 1MB. Everything else byte-identical to r23.
#include <hip/hip_runtime.h>
#include <cstdint>

#define TSIZE (1u << 22)
#define TMASK (TSIZE - 1u)
#define P1 2654435761u
#define P2 805459861u

typedef _Float16 f16x8 __attribute__((ext_vector_type(8)));
typedef _Float16 f16x4 __attribute__((ext_vector_type(4)));
typedef float    f32x4 __attribute__((ext_vector_type(4)));
typedef float    f32x8 __attribute__((ext_vector_type(8)));
typedef float    f32x16 __attribute__((ext_vector_type(16)));
typedef uint32_t u32x8 __attribute__((ext_vector_type(8)));
typedef unsigned long long u64;

// packed-weight layout (halfs) inside d_ws
#define W0_OFF 0        // [256][64]  16x16-order (K remapped: 0..31 grid, 32..43 aux)
#define W1_OFF 16384
#define W2_OFF 81920
#define W3_OFF 147456
#define W4_OFF 212992   // [16][256] (rows padded 3->16)
#define PACK_TOTAL 217088
#define W32_BASE 217088           // 3 layers x 65536 halfs, 32x32 A-frag order
#define W32_TOTAL 196608          // weights end at byte 827392 (< 1 MB)

// 2-bit tables (1 B/entry, 4 MB/level) + featG + auxG in d_ws
#define TB2_BYTE_OFF 1048576ull   // 1 MB -- past all weight packs (r23 bugfix)
#define TB2_BYTES    (8ull * TSIZE)   // 32 MB
#define Q2SCALE 15000.0f
#define QOFF    1.0e-4f
#define FEATG_BYTE_OFF (TB2_BYTE_OFF + TB2_BYTES)

#define MLP_SMEM 65536   // act [128][512B]

// convert_all block partition
#define CV_SWEEP_BLKS 20480   // levels 3..7: 5*4M entries / 4 per thread / 256
#define CV_LAT_BLKS   1233    // lattice lvls 0..2 (4913+35937+274625 = 315475)
#define CV_WB   (CV_SWEEP_BLKS + CV_LAT_BLKS)         // 16x16 pack base
#define CV_W_CNT ((PACK_TOTAL + 255) / 256)           // 848
#define CV_W32B (CV_WB + CV_W_CNT)                    // 32x32 pack base
#define CV_W32_CNT (W32_TOTAL / 256)                  // 768
#define CV_AUX  (CV_W32B + CV_W32_CNT)                // aux base

__device__ inline int swz(int row) {
    return (((row >> 2) & 3) << 5) | ((row & 1) << 4);
}

__device__ inline void lbar() {
    asm volatile("s_waitcnt lgkmcnt(0)" ::: "memory");
    __builtin_amdgcn_s_barrier();
    asm volatile("" ::: "memory");
}

__device__ inline u32x8 hash8v(float x, float y, float z, float res) {
    float px = x * res, py = y * res, pz = z * res;
    uint32_t hx0 = (uint32_t)(int)floorf(px), hx1 = hx0 + 1u;
    uint32_t hy0 = (uint32_t)(int)floorf(py) * P1, hy1 = hy0 + P1;
    uint32_t hz0 = (uint32_t)(int)floorf(pz) * P2, hz1 = hz0 + P2;
    u32x8 h;
    h[0] = (hx0 ^ hy0 ^ hz0) & TMASK; h[1] = (hx0 ^ hy0 ^ hz1) & TMASK;
    h[2] = (hx0 ^ hy1 ^ hz0) & TMASK; h[3] = (hx0 ^ hy1 ^ hz1) & TMASK;
    h[4] = (hx1 ^ hy0 ^ hz0) & TMASK; h[5] = (hx1 ^ hy0 ^ hz1) & TMASK;
    h[6] = (hx1 ^ hy1 ^ hz0) & TMASK; h[7] = (hx1 ^ hy1 ^ hz1) & TMASK;
    return h;
}
__device__ inline f32x8 wts8v(float x, float y, float z, float res) {
    float px = x * res, py = y * res, pz = z * res;
    float wx = px - floorf(px), wy = py - floorf(py), wz = pz - floorf(pz);
    float ux = 1.f - wx, uy = 1.f - wy, uz = 1.f - wz;
    f32x8 w;
    w[0] = ux * uy * uz; w[1] = ux * uy * wz; w[2] = ux * wy * uz; w[3] = ux * wy * wz;
    w[4] = wx * uy * uz; w[5] = wx * uy * wz; w[6] = wx * wy * uz; w[7] = wx * wy * wz;
    return w;
}

__device__ inline uint32_t q2bit(float v) {
    float f = (v + QOFF) * Q2SCALE + 0.5f;
    f = fminf(fmaxf(f, 0.f), 3.f);
    return (uint32_t)f;
}

// ------------- merged pre-pass: tables + 16/32 weight packs + aux build -------------
__global__ __launch_bounds__(256) void convert_all(
    const float* __restrict__ TBL,
    const float* __restrict__ W0, const float* __restrict__ W1,
    const float* __restrict__ W2, const float* __restrict__ W3,
    const float* __restrict__ W4,
    const float* __restrict__ X,  const float* __restrict__ WI,
    const float* __restrict__ NRM, const float* __restrict__ FD,
    _Float16* __restrict__ ws, uint32_t* __restrict__ tb2,
    u64* __restrict__ AUXG, int N)
{
    if (blockIdx.x < CV_SWEEP_BLKS) {
        size_t i = (size_t)blockIdx.x * 256 + threadIdx.x;   // 0 .. 5.24M-1
        size_t e = 3ull * TSIZE + i * 4;                     // entry base (lvl>=3)
        const f32x4* src = (const f32x4*)TBL + e;
        f32x4 a = __builtin_nontemporal_load(src);
        f32x4 b = __builtin_nontemporal_load(src + 1);
        f32x4 c = __builtin_nontemporal_load(src + 2);
        f32x4 d = __builtin_nontemporal_load(src + 3);
        auto pk = [&](f32x4 x_) -> uint32_t {
            return q2bit(x_[0]) | (q2bit(x_[1]) << 2) | (q2bit(x_[2]) << 4) | (q2bit(x_[3]) << 6);
        };
        tb2[(3ull * TSIZE) / 4 + i] = pk(a) | (pk(b) << 8) | (pk(c) << 16) | (pk(d) << 24);
        return;
    }
    if (blockIdx.x < CV_WB) {
        // lattice convert: lvl0 17^3, lvl1 33^3, lvl2 65^3 (collisions benign)
        int idx = (blockIdx.x - CV_SWEEP_BLKS) * 256 + threadIdx.x;
        int lvl, vx, vy, vz;
        if (idx < 4913) {
            lvl = 0;
            vz = idx % 17; int r = idx / 17;
            vy = r % 17;  vx = r / 17;
        } else if (idx < 4913 + 35937) {
            lvl = 1;
            int v = idx - 4913;
            vz = v % 33; int r = v / 33;
            vy = r % 33;  vx = r / 33;
        } else if (idx < 4913 + 35937 + 274625) {
            lvl = 2;
            int v = idx - 4913 - 35937;
            vz = v % 65; int r = v / 65;
            vy = r % 65;  vx = r / 65;
        } else return;
        uint32_t h = ((uint32_t)vx ^ ((uint32_t)vy * P1) ^ ((uint32_t)vz * P2)) & TMASK;
        size_t e = (size_t)lvl * TSIZE + h;
        f32x4 g = ((const f32x4*)TBL)[e];
        uint32_t bq = q2bit(g[0]) | (q2bit(g[1]) << 2) | (q2bit(g[2]) << 4) | (q2bit(g[3]) << 6);
        ((unsigned char*)tb2)[e] = (unsigned char)bq;
        return;
    }
    if (blockIdx.x >= CV_AUX) {
        // aux build: 1 point/thread, coalesced 64B writes
        long p = (long)(blockIdx.x - CV_AUX) * 256 + threadIdx.x;
        if (p >= N) return;
        float x0 = X[p * 3], y0 = X[p * 3 + 1], z0 = X[p * 3 + 2];
        float wa = WI[p * 3], wb = WI[p * 3 + 1], wc = WI[p * 3 + 2];
        float na = NRM[p * 3], nb = NRM[p * 3 + 1], nc = NRM[p * 3 + 2];
        float fa = FD[p * 3], fb = FD[p * 3 + 1], fc = FD[p * 3 + 2];
        f16x8 a07{(_Float16)x0, (_Float16)y0, (_Float16)z0, (_Float16)wa,
                  (_Float16)wb, (_Float16)wc, (_Float16)na, (_Float16)nb};
        f16x8 a8f{(_Float16)nc, (_Float16)fa, (_Float16)fb, (_Float16)fc,
                  (_Float16)0.f, (_Float16)0.f, (_Float16)0.f, (_Float16)0.f};
        u64* ar = &AUXG[p * 8];
        ar[0] = ((u64*)&a07)[0]; ar[1] = ((u64*)&a07)[1];
        ar[2] = ((u64*)&a8f)[0]; ar[3] = ((u64*)&a8f)[1];
        ar[4] = 0ull; ar[5] = 0ull; ar[6] = 0ull; ar[7] = 0ull;
        return;
    }
    if (blockIdx.x >= CV_W32B) {
        // 32x32 A-frag pack for W1..W3: dest ws[W32_BASE + g2];
        // g2 = layer*65536 + ((nt*16+ks)*64 + lane)*8 + j
        // holds W[nt*32 + (lane&31)][ks*16 + (lane>>5)*8 + j]
        int g2 = (blockIdx.x - CV_W32B) * 256 + threadIdx.x;
        if (g2 >= W32_TOTAL) return;
        int layer = g2 >> 16;
        int local = g2 & 65535;
        int j    = local & 7;
        int lane = (local >> 3) & 63;
        int t    = local >> 9;          // nt*16 + ks
        int ks   = t & 15, nt = t >> 4;
        int o = nt * 32 + (lane & 31);
        int k = ks * 16 + ((lane >> 5) << 3) + j;
        const float* Wl = (layer == 0) ? W1 : (layer == 1) ? W2 : W3;
        ws[W32_BASE + g2] = (_Float16)Wl[o * 256 + k];
        return;
    }
    int gid = (blockIdx.x - CV_WB) * 256 + threadIdx.x;
    if (gid >= PACK_TOTAL) return;
    const int   offs[6] = {W0_OFF, W1_OFF, W2_OFF, W3_OFF, W4_OFF, PACK_TOTAL};
    const int   outR[5] = {256, 256, 256, 256, 3};
    const int   kR[5]   = {44, 256, 256, 256, 256};
    const int   kst[5]  = {2, 8, 8, 8, 8};
    const float* Ws[5]  = {W0, W1, W2, W3, W4};
    int l = 0;
    while (gid >= offs[l + 1]) ++l;
    int local = gid - offs[l];
    int j    = local & 7;
    int lane = (local >> 3) & 63;
    int t    = local >> 9;
    int ks   = t & (kst[l] - 1);
    int cf   = t / kst[l];
    int o = cf * 16 + (lane & 15);
    int k = ks * 32 + ((lane >> 4) << 3) + j;
    float v = 0.f;
    if (l == 0) {
        int kk = (k < 32) ? (12 + k) : ((k < 44) ? (k - 32) : -1);
        if (o < 256 && kk >= 0) v = W0[o * 44 + kk];
    } else {
        if (o < outR[l] && k < kR[l]) v = Ws[l][o * kR[l] + k];
    }
    ws[gid] = (_Float16)v;
}

// ------------- convoyed encode (r20-lean, X only): featG[8][N] u64 -------------
__global__ __launch_bounds__(1024, 4) void encode_conv(
    const float* __restrict__ X,
    const unsigned char* __restrict__ TB2,
    u64* __restrict__ FEATG, int N)
{
    const int tid = threadIdx.x;
    long m = (long)N - 1;
    long p0 = (long)blockIdx.x * 2048 + tid;        if (p0 > m) p0 = m;
    long p1 = (long)blockIdx.x * 2048 + 1024 + tid; if (p1 > m) p1 = m;

    float x0 = X[p0 * 3], y0 = X[p0 * 3 + 1], z0 = X[p0 * 3 + 2];
    float x1 = X[p1 * 3], y1 = X[p1 * 3 + 1], z1 = X[p1 * 3 + 2];

    const float inv = 1.0f / Q2SCALE;
    #pragma unroll 1
    for (int lvl = 0; lvl < 8; ++lvl) {
        float res = (float)(16 << lvl);
        const unsigned char* tq = TB2 + ((size_t)lvl << 22);
        u32x8 h0 = hash8v(x0, y0, z0, res);
        u32x8 h1 = hash8v(x1, y1, z1, res);
        u32x8 g0, g1;
        g0[0] = tq[h0[0]]; g0[1] = tq[h0[1]]; g0[2] = tq[h0[2]]; g0[3] = tq[h0[3]];
        g0[4] = tq[h0[4]]; g0[5] = tq[h0[5]]; g0[6] = tq[h0[6]]; g0[7] = tq[h0[7]];
        g1[0] = tq[h1[0]]; g1[1] = tq[h1[1]]; g1[2] = tq[h1[2]]; g1[3] = tq[h1[3]];
        g1[4] = tq[h1[4]]; g1[5] = tq[h1[5]]; g1[6] = tq[h1[6]]; g1[7] = tq[h1[7]];
        f32x8 w0 = wts8v(x0, y0, z0, res);
        f32x8 w1 = wts8v(x1, y1, z1, res);
        #define DQ(gg, ww) { uint32_t u_ = (gg); float w_ = (ww);               \
            s0 += (float)(u_ & 3u) * w_;  s1 += (float)((u_ >> 2) & 3u) * w_;   \
            s2 += (float)((u_ >> 4) & 3u) * w_; s3 += (float)((u_ >> 6) & 3u) * w_; }
        {
            float s0 = 0.f, s1 = 0.f, s2 = 0.f, s3 = 0.f;
            DQ(g0[0], w0[0]) DQ(g0[1], w0[1]) DQ(g0[2], w0[2]) DQ(g0[3], w0[3])
            DQ(g0[4], w0[4]) DQ(g0[5], w0[5]) DQ(g0[6], w0[6]) DQ(g0[7], w0[7])
            f16x4 fv{(_Float16)(s0 * inv - QOFF), (_Float16)(s1 * inv - QOFF),
                     (_Float16)(s2 * inv - QOFF), (_Float16)(s3 * inv - QOFF)};
            *(f16x4*)&FEATG[(size_t)lvl * N + p0] = fv;
        }
        {
            float s0 = 0.f, s1 = 0.f, s2 = 0.f, s3 = 0.f;
            DQ(g1[0], w1[0]) DQ(g1[1], w1[1]) DQ(g1[2], w1[2]) DQ(g1[3], w1[3])
            DQ(g1[4], w1[4]) DQ(g1[5], w1[5]) DQ(g1[6], w1[6]) DQ(g1[7], w1[7])
            f16x4 fv{(_Float16)(s0 * inv - QOFF), (_Float16)(s1 * inv - QOFF),
                     (_Float16)(s2 * inv - QOFF), (_Float16)(s3 * inv - QOFF)};
            *(f16x4*)&FEATG[(size_t)lvl * N + p1] = fv;
        }
        #undef DQ
        __builtin_amdgcn_s_barrier();   // level convoy
    }
}

// ------------- in-place big layer via 32x32x16 MFMA -------------
// D[2 ntile][2 ptile] = mfma32(W_frag, act_frag); per wave: 64 neurons x 64 pts.
// A(W): lane holds W[nt*32+(l&31)][ks*16+(l>>5)*8+j]  (pre-packed 32-order)
// B(act): lane holds act[pt_row][same k] -> 16B LDS read
// D: reg r: neuron_in_tile=(r&3)+8*(r>>2)+4*(l>>5), point_in_tile=l&31
__device__ inline void clayer32(char* __restrict__ act,
                                const f16x8* __restrict__ wp,
                                const float* __restrict__ B,
                                int ng, int pg, int lane)
{
    const int hi = lane >> 5, l31 = lane & 31;
    f32x16 accA0, accA1, accB0, accB1;
    #pragma unroll
    for (int i = 0; i < 16; ++i) { accA0[i] = 0.f; accA1[i] = 0.f; accB0[i] = 0.f; accB1[i] = 0.f; }
    const int nt0 = ng * 2, nt1 = ng * 2 + 1;
    #pragma unroll 4
    for (int ks = 0; ks < 16; ++ks) {
        f16x8 wA = wp[(nt0 * 16 + ks) * 64 + lane];
        f16x8 wB = wp[(nt1 * 16 + ks) * 64 + lane];
        int kb = ks * 32 + hi * 16;
        int r0 = pg * 64 + l31;
        int r1 = pg * 64 + 32 + l31;
        f16x8 b0 = *(const f16x8*)(act + r0 * 512 + (kb ^ swz(r0)));
        f16x8 b1 = *(const f16x8*)(act + r1 * 512 + (kb ^ swz(r1)));
        accA0 = __builtin_amdgcn_mfma_f32_32x32x16_f16(wA, b0, accA0, 0, 0, 0);
        accA1 = __builtin_amdgcn_mfma_f32_32x32x16_f16(wA, b1, accA1, 0, 0, 0);
        accB0 = __builtin_amdgcn_mfma_f32_32x32x16_f16(wB, b0, accB0, 0, 0, 0);
        accB1 = __builtin_amdgcn_mfma_f32_32x32x16_f16(wB, b1, accB1, 0, 0, 0);
    }
    lbar();   // all waves' reads complete before any in-place write
    #define EPI(ACC, NT, PT) {                                                   \
        _Pragma("unroll")                                                        \
        for (int q = 0; q < 4; ++q) {                                            \
            int nb = ng * 64 + (NT) * 32 + q * 8 + hi * 4;                       \
            f32x4 bv = *(const f32x4*)(B + nb);                                  \
            int ptr_ = pg * 64 + (PT) * 32 + l31;                                \
            f16x4 o;                                                             \
            _Pragma("unroll")                                                    \
            for (int r = 0; r < 4; ++r)                                          \
                o[r] = (_Float16)fmaxf(ACC[q * 4 + r] + bv[r], 0.f);             \
            *(f16x4*)(act + ptr_ * 512 + ((nb * 2) ^ swz(ptr_))) = o;            \
        } }
    EPI(accA0, 0, 0) EPI(accA1, 0, 1) EPI(accB0, 1, 0) EPI(accB1, 1, 1)
    #undef EPI
    lbar();
}

// ------------- MLP kernel: 512 thr / 8 waves / 64 KB LDS -------------
__global__ __launch_bounds__(512, 2) void nrfield_mlp(
    const u64* __restrict__ FEATG, const u64* __restrict__ AUXG,
    const float* __restrict__ B0, const float* __restrict__ B1,
    const float* __restrict__ B2, const float* __restrict__ B3,
    const float* __restrict__ B4,
    const _Float16* __restrict__ WS, float* __restrict__ OUT, int N)
{
    extern __shared__ char act[];   // [128][512B], in-place across layers
    const int wave = threadIdx.x >> 6, lane = threadIdx.x & 63;
    const int h = lane >> 4, lp = lane & 15;
    const int ng = wave & 3, pg = wave >> 2;   // 4 neuron-groups x 2 pt-groups
    const long pbase = (long)blockIdx.x * 1024;

    const f16x8* wsW0 = (const f16x8*)(WS + W0_OFF);
    const f16x8* wsW1 = (const f16x8*)(WS + W32_BASE);
    const f16x8* wsW2 = (const f16x8*)(WS + W32_BASE + 65536);
    const f16x8* wsW3 = (const f16x8*)(WS + W32_BASE + 131072);
    const f16x8* wsW4 = (const f16x8*)(WS + W4_OFF);
    const float b40 = B4[0], b41 = B4[1], b42 = B4[2];

    for (int ci = 0; ci < 8; ++ci) {
        const long cb = pbase + (long)ci * 128;

        // ---- L0 (16x16): B-frags direct from featG/auxG; A = W0 frags ----
        f32x4 acc[4][4];
        #pragma unroll
        for (int i = 0; i < 4; ++i)
            #pragma unroll
            for (int j = 0; j < 4; ++j)
                acc[i][j] = f32x4{0.f, 0.f, 0.f, 0.f};
        {   // grid-feature K-half (ks=0)
            f16x8 w00 = wsW0[((ng * 4 + 0) * 2 + 0) * 64 + lane];
            f16x8 w10 = wsW0[((ng * 4 + 1) * 2 + 0) * 64 + lane];
            f16x8 w20 = wsW0[((ng * 4 + 2) * 2 + 0) * 64 + lane];
            f16x8 w30 = wsW0[((ng * 4 + 3) * 2 + 0) * 64 + lane];
            #pragma unroll
            for (int nf = 0; nf < 4; ++nf) {
                long p = cb + pg * 64 + nf * 16 + lp;
                if (p > (long)N - 1) p = N - 1;
                u64 q0 = FEATG[(size_t)(2 * h) * N + p];
                u64 q1 = FEATG[(size_t)(2 * h + 1) * N + p];
                f16x8 bg;
                ((u64*)&bg)[0] = q0; ((u64*)&bg)[1] = q1;
                acc[0][nf] = __builtin_amdgcn_mfma_f32_16x16x32_f16(w00, bg, acc[0][nf], 0, 0, 0);
                acc[1][nf] = __builtin_amdgcn_mfma_f32_16x16x32_f16(w10, bg, acc[1][nf], 0, 0, 0);
                acc[2][nf] = __builtin_amdgcn_mfma_f32_16x16x32_f16(w20, bg, acc[2][nf], 0, 0, 0);
                acc[3][nf] = __builtin_amdgcn_mfma_f32_16x16x32_f16(w30, bg, acc[3][nf], 0, 0, 0);
            }
        }
        {   // aux K-half (ks=1): coalesced u64 reads from pre-built auxG
            f16x8 w01 = wsW0[((ng * 4 + 0) * 2 + 1) * 64 + lane];
            f16x8 w11 = wsW0[((ng * 4 + 1) * 2 + 1) * 64 + lane];
            f16x8 w21 = wsW0[((ng * 4 + 2) * 2 + 1) * 64 + lane];
            f16x8 w31 = wsW0[((ng * 4 + 3) * 2 + 1) * 64 + lane];
            #pragma unroll
            for (int nf = 0; nf < 4; ++nf) {
                long p = cb + pg * 64 + nf * 16 + lp;
                if (p > (long)N - 1) p = N - 1;
                u64 q2 = AUXG[(size_t)p * 8 + 2 * h];
                u64 q3 = AUXG[(size_t)p * 8 + 2 * h + 1];
                f16x8 ba;
                ((u64*)&ba)[0] = q2; ((u64*)&ba)[1] = q3;
                acc[0][nf] = __builtin_amdgcn_mfma_f32_16x16x32_f16(w01, ba, acc[0][nf], 0, 0, 0);
                acc[1][nf] = __builtin_amdgcn_mfma_f32_16x16x32_f16(w11, ba, acc[1][nf], 0, 0, 0);
                acc[2][nf] = __builtin_amdgcn_mfma_f32_16x16x32_f16(w21, ba, acc[2][nf], 0, 0, 0);
                acc[3][nf] = __builtin_amdgcn_mfma_f32_16x16x32_f16(w31, ba, acc[3][nf], 0, 0, 0);
            }
        }
        #pragma unroll
        for (int cf = 0; cf < 4; ++cf) {
            int nb = ng * 64 + cf * 16 + h * 4;
            f32x4 bv = *(const f32x4*)(B0 + nb);
            #pragma unroll
            for (int nf = 0; nf < 4; ++nf) {
                int pt = pg * 64 + nf * 16 + lp;
                f16x4 o;
                #pragma unroll
                for (int r = 0; r < 4; ++r)
                    o[r] = (_Float16)fmaxf(acc[cf][nf][r] + bv[r], 0.f);
                *(f16x4*)(act + pt * 512 + ((nb * 2) ^ swz(pt))) = o;
            }
        }
        lbar();

        // ---- L1..L3 in-place, 32x32x16 MFMA ----
        clayer32(act, wsW1, B1, ng, pg, lane);
        clayer32(act, wsW2, B2, ng, pg, lane);
        clayer32(act, wsW3, B3, ng, pg, lane);

        // ---- final (16x16): wave w -> pts w*16..+15 (of 128); D[neuron][pt] ----
        {
            f32x4 a4 = f32x4{0.f, 0.f, 0.f, 0.f};
            int row = wave * 16 + lp;
            #pragma unroll 2
            for (int ks = 0; ks < 8; ++ks) {
                f16x8 w4 = wsW4[ks * 64 + lane];
                int kb = ks * 64 + h * 16;
                f16x8 a = *(const f16x8*)(act + row * 512 + (kb ^ swz(row)));
                a4 = __builtin_amdgcn_mfma_f32_16x16x32_f16(w4, a, a4, 0, 0, 0);
            }
            if (h == 0) {
                long pt = cb + wave * 16 + lp;
                if (pt < N) {
                    OUT[pt * 3 + 0] = fabsf(a4[0] + b40);
                    OUT[pt * 3 + 1] = fabsf(a4[1] + b41);
                    OUT[pt * 3 + 2] = fabsf(a4[2] + b42);
                }
            }
        }
        lbar();   // final's act reads drained before next chunk's L0 writes
    }
}

// ================= launch =================
extern "C" void kernel_launch(void* const* d_in, const int* in_sizes, int n_in,
                              void* d_out, int out_size, void* d_ws, size_t ws_size,
                              hipStream_t stream)
{
    const float* X   = (const float*)d_in[0];
    const float* WI  = (const float*)d_in[1];
    const float* NRM = (const float*)d_in[2];
    const float* FD  = (const float*)d_in[3];
    const float* TBL = (const float*)d_in[4];
    const float* W0  = (const float*)d_in[5];
    const float* B0  = (const float*)d_in[6];
    const float* W1  = (const float*)d_in[7];
    const float* B1  = (const float*)d_in[8];
    const float* W2  = (const float*)d_in[9];
    const float* B2  = (const float*)d_in[10];
    const float* W3  = (const float*)d_in[11];
    const float* B3  = (const float*)d_in[12];
    const float* W4  = (const float*)d_in[13];
    const float* B4  = (const float*)d_in[14];
    float* OUT = (float*)d_out;

    int N = in_sizes[0] / 3;
    _Float16* ws = (_Float16*)d_ws;
    uint32_t* tb2 = (uint32_t*)((char*)d_ws + TB2_BYTE_OFF);
    u64* featg = (u64*)((char*)d_ws + FEATG_BYTE_OFF);
    u64* auxg  = featg + (size_t)8 * N;
    // ws usage: <1 MB weights + 32 MB tables + 32 MB featG + 32 MB auxG

    int nAux = (N + 255) / 256;     // 2048 @ N=524288
    convert_all<<<CV_AUX + nAux, 256, 0, stream>>>(
        TBL, W0, W1, W2, W3, W4, X, WI, NRM, FD, ws, tb2, auxg, N);

    int nblkE = (N + 2047) / 2048;  // 256 @ N=524288
    encode_conv<<<nblkE, 1024, 0, stream>>>(X, (const unsigned char*)tb2,
                                            featg, N);

    int nblkM = (N + 1023) / 1024;  // 512 @ N=524288 -> 2 blocks/CU
    hipFuncSetAttribute((const void*)nrfield_mlp,
                        hipFuncAttributeMaxDynamicSharedMemorySize, MLP_SMEM);
    nrfield_mlp<<<nblkM, 512, MLP_SMEM, stream>>>(featg, auxg,
                                                  B0, B1, B2, B3, B4,
                                                  ws, OUT, N);
}

// Round 25
// 462.204 us; speedup vs baseline: 1.0713x; 1.0713x over previous
//
// NRField rev25: REVERT to r22 (champion, 462.6us). r24 proved 32x32 MFMA a
// regression (MLP 317 vs 295 - the MFMA pipe at 31% util was never binding;
// the cost is the barrier-locked layer structure). Ledger: setprio null (r21),
// encode pipelining null (r19), overlap architectures worse (r13/r15/r16),
// traffic at compulsory floors (r20/r22). This is the proven best.
#include <hip/hip_runtime.h>
#include <cstdint>

#define TSIZE (1u << 22)
#define TMASK (TSIZE - 1u)
#define P1 2654435761u
#define P2 805459861u

typedef _Float16 f16x8 __attribute__((ext_vector_type(8)));
typedef _Float16 f16x4 __attribute__((ext_vector_type(4)));
typedef float    f32x4 __attribute__((ext_vector_type(4)));
typedef float    f32x8 __attribute__((ext_vector_type(8)));
typedef uint32_t u32x8 __attribute__((ext_vector_type(8)));
typedef unsigned long long u64;

// packed-weight layout offsets (in halfs) inside d_ws
#define W0_OFF 0        // [256][64]  (K remapped: 0..31 grid, 32..43 aux)
#define W1_OFF 16384
#define W2_OFF 81920
#define W3_OFF 147456
#define W4_OFF 212992   // [16][256] (rows padded 3->16)
#define PACK_TOTAL 217088

// 2-bit tables (1 B/entry, 4 MB/level) + featG + auxG in d_ws
#define TB2_BYTE_OFF 524288ull
#define TB2_BYTES    (8ull * TSIZE)   // 32 MB
#define Q2SCALE 15000.0f
#define QOFF    1.0e-4f
#define FEATG_BYTE_OFF (TB2_BYTE_OFF + TB2_BYTES)

#define MLP_SMEM 65536   // act [128][512B]

// convert_all block partition
#define CV_SWEEP_BLKS 24576   // levels 2..7: 6*4M entries / 4 per thread / 256
#define CV_LAT_BLKS   160     // lattice for levels 0..1 (40850 entries)
#define CV_WB  (CV_SWEEP_BLKS + CV_LAT_BLKS)          // weights base
#define CV_W_CNT ((PACK_TOTAL + 255) / 256)           // 848
#define CV_AUX (CV_WB + CV_W_CNT)                     // aux base

__device__ inline int swz(int row) {
    return (((row >> 2) & 3) << 5) | ((row & 1) << 4);
}

__device__ inline void lbar() {
    asm volatile("s_waitcnt lgkmcnt(0)" ::: "memory");
    __builtin_amdgcn_s_barrier();
    asm volatile("" ::: "memory");
}

__device__ inline u32x8 hash8v(float x, float y, float z, float res) {
    float px = x * res, py = y * res, pz = z * res;
    uint32_t hx0 = (uint32_t)(int)floorf(px), hx1 = hx0 + 1u;
    uint32_t hy0 = (uint32_t)(int)floorf(py) * P1, hy1 = hy0 + P1;
    uint32_t hz0 = (uint32_t)(int)floorf(pz) * P2, hz1 = hz0 + P2;
    u32x8 h;
    h[0] = (hx0 ^ hy0 ^ hz0) & TMASK; h[1] = (hx0 ^ hy0 ^ hz1) & TMASK;
    h[2] = (hx0 ^ hy1 ^ hz0) & TMASK; h[3] = (hx0 ^ hy1 ^ hz1) & TMASK;
    h[4] = (hx1 ^ hy0 ^ hz0) & TMASK; h[5] = (hx1 ^ hy0 ^ hz1) & TMASK;
    h[6] = (hx1 ^ hy1 ^ hz0) & TMASK; h[7] = (hx1 ^ hy1 ^ hz1) & TMASK;
    return h;
}
__device__ inline f32x8 wts8v(float x, float y, float z, float res) {
    float px = x * res, py = y * res, pz = z * res;
    float wx = px - floorf(px), wy = py - floorf(py), wz = pz - floorf(pz);
    float ux = 1.f - wx, uy = 1.f - wy, uz = 1.f - wz;
    f32x8 w;
    w[0] = ux * uy * uz; w[1] = ux * uy * wz; w[2] = ux * wy * uz; w[3] = ux * wy * wz;
    w[4] = wx * uy * uz; w[5] = wx * uy * wz; w[6] = wx * wy * uz; w[7] = wx * wy * wz;
    return w;
}

__device__ inline uint32_t q2bit(float v) {
    float f = (v + QOFF) * Q2SCALE + 0.5f;
    f = fminf(fmaxf(f, 0.f), 3.f);
    return (uint32_t)f;
}

// ------------- merged pre-pass: tables + weights + aux build -------------
__global__ __launch_bounds__(256) void convert_all(
    const float* __restrict__ TBL,
    const float* __restrict__ W0, const float* __restrict__ W1,
    const float* __restrict__ W2, const float* __restrict__ W3,
    const float* __restrict__ W4,
    const float* __restrict__ X,  const float* __restrict__ WI,
    const float* __restrict__ NRM, const float* __restrict__ FD,
    _Float16* __restrict__ ws, uint32_t* __restrict__ tb2,
    u64* __restrict__ AUXG, int N)
{
    if (blockIdx.x < CV_SWEEP_BLKS) {
        size_t i = (size_t)blockIdx.x * 256 + threadIdx.x;   // 0 .. 6.29M-1
        size_t e = 2ull * TSIZE + i * 4;                     // entry base (lvl>=2)
        const f32x4* src = (const f32x4*)TBL + e;
        f32x4 a = __builtin_nontemporal_load(src);
        f32x4 b = __builtin_nontemporal_load(src + 1);
        f32x4 c = __builtin_nontemporal_load(src + 2);
        f32x4 d = __builtin_nontemporal_load(src + 3);
        auto pk = [&](f32x4 x_) -> uint32_t {
            return q2bit(x_[0]) | (q2bit(x_[1]) << 2) | (q2bit(x_[2]) << 4) | (q2bit(x_[3]) << 6);
        };
        tb2[TSIZE / 2 + i] = pk(a) | (pk(b) << 8) | (pk(c) << 16) | (pk(d) << 24);
        return;
    }
    if (blockIdx.x < CV_WB) {
        // lattice convert for levels 0 (17^3) and 1 (33^3)
        int idx = (blockIdx.x - CV_SWEEP_BLKS) * 256 + threadIdx.x;
        int lvl, vx, vy, vz;
        if (idx < 4913) {                 // 17^3
            lvl = 0;
            vz = idx % 17; int r = idx / 17;
            vy = r % 17;  vx = r / 17;
        } else if (idx < 4913 + 35937) {  // 33^3
            lvl = 1;
            int v = idx - 4913;
            vz = v % 33; int r = v / 33;
            vy = r % 33;  vx = r / 33;
        } else return;
        uint32_t h = ((uint32_t)vx ^ ((uint32_t)vy * P1) ^ ((uint32_t)vz * P2)) & TMASK;
        size_t e = (size_t)lvl * TSIZE + h;
        f32x4 g = ((const f32x4*)TBL)[e];
        uint32_t bq = q2bit(g[0]) | (q2bit(g[1]) << 2) | (q2bit(g[2]) << 4) | (q2bit(g[3]) << 6);
        ((unsigned char*)tb2)[e] = (unsigned char)bq;
        return;
    }
    if (blockIdx.x >= CV_AUX) {
        // aux build: 1 point/thread, coalesced 64B writes
        long p = (long)(blockIdx.x - CV_AUX) * 256 + threadIdx.x;
        if (p >= N) return;
        float x0 = X[p * 3], y0 = X[p * 3 + 1], z0 = X[p * 3 + 2];
        float wa = WI[p * 3], wb = WI[p * 3 + 1], wc = WI[p * 3 + 2];
        float na = NRM[p * 3], nb = NRM[p * 3 + 1], nc = NRM[p * 3 + 2];
        float fa = FD[p * 3], fb = FD[p * 3 + 1], fc = FD[p * 3 + 2];
        f16x8 a07{(_Float16)x0, (_Float16)y0, (_Float16)z0, (_Float16)wa,
                  (_Float16)wb, (_Float16)wc, (_Float16)na, (_Float16)nb};
        f16x8 a8f{(_Float16)nc, (_Float16)fa, (_Float16)fb, (_Float16)fc,
                  (_Float16)0.f, (_Float16)0.f, (_Float16)0.f, (_Float16)0.f};
        u64* ar = &AUXG[p * 8];
        ar[0] = ((u64*)&a07)[0]; ar[1] = ((u64*)&a07)[1];
        ar[2] = ((u64*)&a8f)[0]; ar[3] = ((u64*)&a8f)[1];
        ar[4] = 0ull; ar[5] = 0ull; ar[6] = 0ull; ar[7] = 0ull;
        return;
    }
    int gid = (blockIdx.x - CV_WB) * 256 + threadIdx.x;
    if (gid >= PACK_TOTAL) return;
    const int   offs[6] = {W0_OFF, W1_OFF, W2_OFF, W3_OFF, W4_OFF, PACK_TOTAL};
    const int   outR[5] = {256, 256, 256, 256, 3};
    const int   kR[5]   = {44, 256, 256, 256, 256};
    const int   kst[5]  = {2, 8, 8, 8, 8};
    const float* Ws[5]  = {W0, W1, W2, W3, W4};
    int l = 0;
    while (gid >= offs[l + 1]) ++l;
    int local = gid - offs[l];
    int j    = local & 7;
    int lane = (local >> 3) & 63;
    int t    = local >> 9;
    int ks   = t & (kst[l] - 1);
    int cf   = t / kst[l];
    int o = cf * 16 + (lane & 15);
    int k = ks * 32 + ((lane >> 4) << 3) + j;
    float v = 0.f;
    if (l == 0) {
        int kk = (k < 32) ? (12 + k) : ((k < 44) ? (k - 32) : -1);
        if (o < 256 && kk >= 0) v = W0[o * 44 + kk];
    } else {
        if (o < outR[l] && k < kR[l]) v = Ws[l][o * kR[l] + k];
    }
    ws[gid] = (_Float16)v;
}

// ------------- convoyed encode (r20-lean, X only): featG[8][N] u64 -------------
__global__ __launch_bounds__(1024, 4) void encode_conv(
    const float* __restrict__ X,
    const unsigned char* __restrict__ TB2,
    u64* __restrict__ FEATG, int N)
{
    const int tid = threadIdx.x;
    long m = (long)N - 1;
    long p0 = (long)blockIdx.x * 2048 + tid;        if (p0 > m) p0 = m;
    long p1 = (long)blockIdx.x * 2048 + 1024 + tid; if (p1 > m) p1 = m;

    float x0 = X[p0 * 3], y0 = X[p0 * 3 + 1], z0 = X[p0 * 3 + 2];
    float x1 = X[p1 * 3], y1 = X[p1 * 3 + 1], z1 = X[p1 * 3 + 2];

    const float inv = 1.0f / Q2SCALE;
    #pragma unroll 1
    for (int lvl = 0; lvl < 8; ++lvl) {
        float res = (float)(16 << lvl);
        const unsigned char* tq = TB2 + ((size_t)lvl << 22);
        u32x8 h0 = hash8v(x0, y0, z0, res);
        u32x8 h1 = hash8v(x1, y1, z1, res);
        u32x8 g0, g1;
        g0[0] = tq[h0[0]]; g0[1] = tq[h0[1]]; g0[2] = tq[h0[2]]; g0[3] = tq[h0[3]];
        g0[4] = tq[h0[4]]; g0[5] = tq[h0[5]]; g0[6] = tq[h0[6]]; g0[7] = tq[h0[7]];
        g1[0] = tq[h1[0]]; g1[1] = tq[h1[1]]; g1[2] = tq[h1[2]]; g1[3] = tq[h1[3]];
        g1[4] = tq[h1[4]]; g1[5] = tq[h1[5]]; g1[6] = tq[h1[6]]; g1[7] = tq[h1[7]];
        f32x8 w0 = wts8v(x0, y0, z0, res);
        f32x8 w1 = wts8v(x1, y1, z1, res);
        #define DQ(gg, ww) { uint32_t u_ = (gg); float w_ = (ww);               \
            s0 += (float)(u_ & 3u) * w_;  s1 += (float)((u_ >> 2) & 3u) * w_;   \
            s2 += (float)((u_ >> 4) & 3u) * w_; s3 += (float)((u_ >> 6) & 3u) * w_; }
        {
            float s0 = 0.f, s1 = 0.f, s2 = 0.f, s3 = 0.f;
            DQ(g0[0], w0[0]) DQ(g0[1], w0[1]) DQ(g0[2], w0[2]) DQ(g0[3], w0[3])
            DQ(g0[4], w0[4]) DQ(g0[5], w0[5]) DQ(g0[6], w0[6]) DQ(g0[7], w0[7])
            f16x4 fv{(_Float16)(s0 * inv - QOFF), (_Float16)(s1 * inv - QOFF),
                     (_Float16)(s2 * inv - QOFF), (_Float16)(s3 * inv - QOFF)};
            *(f16x4*)&FEATG[(size_t)lvl * N + p0] = fv;
        }
        {
            float s0 = 0.f, s1 = 0.f, s2 = 0.f, s3 = 0.f;
            DQ(g1[0], w1[0]) DQ(g1[1], w1[1]) DQ(g1[2], w1[2]) DQ(g1[3], w1[3])
            DQ(g1[4], w1[4]) DQ(g1[5], w1[5]) DQ(g1[6], w1[6]) DQ(g1[7], w1[7])
            f16x4 fv{(_Float16)(s0 * inv - QOFF), (_Float16)(s1 * inv - QOFF),
                     (_Float16)(s2 * inv - QOFF), (_Float16)(s3 * inv - QOFF)};
            *(f16x4*)&FEATG[(size_t)lvl * N + p1] = fv;
        }
        #undef DQ
        __builtin_amdgcn_s_barrier();   // level convoy
    }
}

// ------------- in-place big layer, 8 waves / 128 rows; ks unroll 4 (r18) -------------
__device__ inline void clayer_ip8(char* __restrict__ act,
                                  const f16x8* __restrict__ wp,
                                  const float* __restrict__ B,
                                  int ng, int pg, int lane)
{
    const int h = lane >> 4, lp = lane & 15;
    f32x4 acc[4][4];
    #pragma unroll
    for (int i = 0; i < 4; ++i)
        #pragma unroll
        for (int j = 0; j < 4; ++j)
            acc[i][j] = f32x4{0.f, 0.f, 0.f, 0.f};
    #pragma unroll 4
    for (int ks = 0; ks < 8; ++ks) {
        f16x8 w0_ = wp[((ng * 4 + 0) * 8 + ks) * 64 + lane];
        f16x8 w1_ = wp[((ng * 4 + 1) * 8 + ks) * 64 + lane];
        f16x8 w2_ = wp[((ng * 4 + 2) * 8 + ks) * 64 + lane];
        f16x8 w3_ = wp[((ng * 4 + 3) * 8 + ks) * 64 + lane];
        int kb = ks * 64 + h * 16;
        #pragma unroll
        for (int nf = 0; nf < 4; ++nf) {
            int row = pg * 64 + nf * 16 + lp;
            f16x8 a = *(const f16x8*)(act + row * 512 + (kb ^ swz(row)));
            acc[0][nf] = __builtin_amdgcn_mfma_f32_16x16x32_f16(w0_, a, acc[0][nf], 0, 0, 0);
            acc[1][nf] = __builtin_amdgcn_mfma_f32_16x16x32_f16(w1_, a, acc[1][nf], 0, 0, 0);
            acc[2][nf] = __builtin_amdgcn_mfma_f32_16x16x32_f16(w2_, a, acc[2][nf], 0, 0, 0);
            acc[3][nf] = __builtin_amdgcn_mfma_f32_16x16x32_f16(w3_, a, acc[3][nf], 0, 0, 0);
        }
    }
    lbar();   // all waves' reads complete before any in-place write
    #pragma unroll
    for (int cf = 0; cf < 4; ++cf) {
        int nb = ng * 64 + cf * 16 + h * 4;
        f32x4 bv = *(const f32x4*)(B + nb);
        #pragma unroll
        for (int nf = 0; nf < 4; ++nf) {
            int pt = pg * 64 + nf * 16 + lp;
            f16x4 o;
            #pragma unroll
            for (int r = 0; r < 4; ++r)
                o[r] = (_Float16)fmaxf(acc[cf][nf][r] + bv[r], 0.f);
            *(f16x4*)(act + pt * 512 + ((nb * 2) ^ swz(pt))) = o;
        }
    }
    lbar();
}

// ------------- MLP kernel: 512 thr / 8 waves / 64 KB LDS (r18 L0 restored) -------------
__global__ __launch_bounds__(512, 2) void nrfield_mlp(
    const u64* __restrict__ FEATG, const u64* __restrict__ AUXG,
    const float* __restrict__ B0, const float* __restrict__ B1,
    const float* __restrict__ B2, const float* __restrict__ B3,
    const float* __restrict__ B4,
    const _Float16* __restrict__ WS, float* __restrict__ OUT, int N)
{
    extern __shared__ char act[];   // [128][512B], in-place across layers
    const int wave = threadIdx.x >> 6, lane = threadIdx.x & 63;
    const int h = lane >> 4, lp = lane & 15;
    const int ng = wave & 3, pg = wave >> 2;   // 4 neuron-groups x 2 pt-groups
    const long pbase = (long)blockIdx.x * 1024;

    const f16x8* wsW0 = (const f16x8*)(WS + W0_OFF);
    const f16x8* wsW1 = (const f16x8*)(WS + W1_OFF);
    const f16x8* wsW2 = (const f16x8*)(WS + W2_OFF);
    const f16x8* wsW3 = (const f16x8*)(WS + W3_OFF);
    const f16x8* wsW4 = (const f16x8*)(WS + W4_OFF);
    const float b40 = B4[0], b41 = B4[1], b42 = B4[2];

    for (int ci = 0; ci < 8; ++ci) {
        const long cb = pbase + (long)ci * 128;

        // ---- L0: B-frags direct from featG/auxG; A = W0 frags ----
        f32x4 acc[4][4];
        #pragma unroll
        for (int i = 0; i < 4; ++i)
            #pragma unroll
            for (int j = 0; j < 4; ++j)
                acc[i][j] = f32x4{0.f, 0.f, 0.f, 0.f};
        {   // grid-feature K-half (ks=0)
            f16x8 w00 = wsW0[((ng * 4 + 0) * 2 + 0) * 64 + lane];
            f16x8 w10 = wsW0[((ng * 4 + 1) * 2 + 0) * 64 + lane];
            f16x8 w20 = wsW0[((ng * 4 + 2) * 2 + 0) * 64 + lane];
            f16x8 w30 = wsW0[((ng * 4 + 3) * 2 + 0) * 64 + lane];
            #pragma unroll
            for (int nf = 0; nf < 4; ++nf) {
                long p = cb + pg * 64 + nf * 16 + lp;
                if (p > (long)N - 1) p = N - 1;
                u64 q0 = FEATG[(size_t)(2 * h) * N + p];
                u64 q1 = FEATG[(size_t)(2 * h + 1) * N + p];
                f16x8 bg;
                ((u64*)&bg)[0] = q0; ((u64*)&bg)[1] = q1;
                acc[0][nf] = __builtin_amdgcn_mfma_f32_16x16x32_f16(w00, bg, acc[0][nf], 0, 0, 0);
                acc[1][nf] = __builtin_amdgcn_mfma_f32_16x16x32_f16(w10, bg, acc[1][nf], 0, 0, 0);
                acc[2][nf] = __builtin_amdgcn_mfma_f32_16x16x32_f16(w20, bg, acc[2][nf], 0, 0, 0);
                acc[3][nf] = __builtin_amdgcn_mfma_f32_16x16x32_f16(w30, bg, acc[3][nf], 0, 0, 0);
            }
        }
        {   // aux K-half (ks=1): coalesced u64 reads from pre-built auxG
            f16x8 w01 = wsW0[((ng * 4 + 0) * 2 + 1) * 64 + lane];
            f16x8 w11 = wsW0[((ng * 4 + 1) * 2 + 1) * 64 + lane];
            f16x8 w21 = wsW0[((ng * 4 + 2) * 2 + 1) * 64 + lane];
            f16x8 w31 = wsW0[((ng * 4 + 3) * 2 + 1) * 64 + lane];
            #pragma unroll
            for (int nf = 0; nf < 4; ++nf) {
                long p = cb + pg * 64 + nf * 16 + lp;
                if (p > (long)N - 1) p = N - 1;
                u64 q2 = AUXG[(size_t)p * 8 + 2 * h];
                u64 q3 = AUXG[(size_t)p * 8 + 2 * h + 1];
                f16x8 ba;
                ((u64*)&ba)[0] = q2; ((u64*)&ba)[1] = q3;
                acc[0][nf] = __builtin_amdgcn_mfma_f32_16x16x32_f16(w01, ba, acc[0][nf], 0, 0, 0);
                acc[1][nf] = __builtin_amdgcn_mfma_f32_16x16x32_f16(w11, ba, acc[1][nf], 0, 0, 0);
                acc[2][nf] = __builtin_amdgcn_mfma_f32_16x16x32_f16(w21, ba, acc[2][nf], 0, 0, 0);
                acc[3][nf] = __builtin_amdgcn_mfma_f32_16x16x32_f16(w31, ba, acc[3][nf], 0, 0, 0);
            }
        }
        #pragma unroll
        for (int cf = 0; cf < 4; ++cf) {
            int nb = ng * 64 + cf * 16 + h * 4;
            f32x4 bv = *(const f32x4*)(B0 + nb);
            #pragma unroll
            for (int nf = 0; nf < 4; ++nf) {
                int pt = pg * 64 + nf * 16 + lp;
                f16x4 o;
                #pragma unroll
                for (int r = 0; r < 4; ++r)
                    o[r] = (_Float16)fmaxf(acc[cf][nf][r] + bv[r], 0.f);
                *(f16x4*)(act + pt * 512 + ((nb * 2) ^ swz(pt))) = o;
            }
        }
        lbar();

        // ---- L1..L3 in-place ----
        clayer_ip8(act, wsW1, B1, ng, pg, lane);
        clayer_ip8(act, wsW2, B2, ng, pg, lane);
        clayer_ip8(act, wsW3, B3, ng, pg, lane);

        // ---- final: wave w -> pts w*16..+15 (of 128); D[neuron][pt] ----
        {
            f32x4 a4 = f32x4{0.f, 0.f, 0.f, 0.f};
            int row = wave * 16 + lp;
            #pragma unroll 2
            for (int ks = 0; ks < 8; ++ks) {
                f16x8 w4 = wsW4[ks * 64 + lane];
                int kb = ks * 64 + h * 16;
                f16x8 a = *(const f16x8*)(act + row * 512 + (kb ^ swz(row)));
                a4 = __builtin_amdgcn_mfma_f32_16x16x32_f16(w4, a, a4, 0, 0, 0);
            }
            if (h == 0) {
                long pt = cb + wave * 16 + lp;
                if (pt < N) {
                    OUT[pt * 3 + 0] = fabsf(a4[0] + b40);
                    OUT[pt * 3 + 1] = fabsf(a4[1] + b41);
                    OUT[pt * 3 + 2] = fabsf(a4[2] + b42);
                }
            }
        }
        lbar();   // final's act reads drained before next chunk's L0 writes
    }
}

// ================= launch =================
extern "C" void kernel_launch(void* const* d_in, const int* in_sizes, int n_in,
                              void* d_out, int out_size, void* d_ws, size_t ws_size,
                              hipStream_t stream)
{
    const float* X   = (const float*)d_in[0];
    const float* WI  = (const float*)d_in[1];
    const float* NRM = (const float*)d_in[2];
    const float* FD  = (const float*)d_in[3];
    const float* TBL = (const float*)d_in[4];
    const float* W0  = (const float*)d_in[5];
    const float* B0  = (const float*)d_in[6];
    const float* W1  = (const float*)d_in[7];
    const float* B1  = (const float*)d_in[8];
    const float* W2  = (const float*)d_in[9];
    const float* B2  = (const float*)d_in[10];
    const float* W3  = (const float*)d_in[11];
    const float* B3  = (const float*)d_in[12];
    const float* W4  = (const float*)d_in[13];
    const float* B4  = (const float*)d_in[14];
    float* OUT = (float*)d_out;

    int N = in_sizes[0] / 3;
    _Float16* ws = (_Float16*)d_ws;
    uint32_t* tb2 = (uint32_t*)((char*)d_ws + TB2_BYTE_OFF);
    u64* featg = (u64*)((char*)d_ws + FEATG_BYTE_OFF);
    u64* auxg  = featg + (size_t)8 * N;
    // ws usage: 0.5 MB weights + 32 MB tables + 32 MB featG + 32 MB auxG

    int nAux = (N + 255) / 256;     // 2048 @ N=524288
    convert_all<<<CV_AUX + nAux, 256, 0, stream>>>(
        TBL, W0, W1, W2, W3, W4, X, WI, NRM, FD, ws, tb2, auxg, N);

    int nblkE = (N + 2047) / 2048;  // 256 @ N=524288
    encode_conv<<<nblkE, 1024, 0, stream>>>(X, (const unsigned char*)tb2,
                                            featg, N);

    int nblkM = (N + 1023) / 1024;  // 512 @ N=524288 -> 2 blocks/CU
    hipFuncSetAttribute((const void*)nrfield_mlp,
                        hipFuncAttributeMaxDynamicSharedMemorySize, MLP_SMEM);
    nrfield_mlp<<<nblkM, 512, MLP_SMEM, stream>>>(featg, auxg,
                                                  B0, B1, B2, B3, B4,
                                                  ws, OUT, N);
}